// Round 2
// baseline (119.159 us; speedup 1.0000x reference)
//
#include <hip/hip_runtime.h>
#include <math.h>

// EnGMPHD update kernel for MI355X.
// Inputs (setup_inputs order):
//   d_in[0] means  [N,6]  f32
//   d_in[1] covs   [N,6,6] f32 (unused, shape only)
//   d_in[2] weights [N]   f32 (unused)
//   d_in[3] measurements [M,3] f32
//   d_in[4] measurements_mask [M] bool/int
//   d_in[5] R [3,3] f32
// Outputs concatenated: pts [M,N,6], logw [M,N], covs_out [M,N,6,6]  (f32)
//
// Structure (round 2):
//   1. stats_kernel: f64 block reduction of sum_x / sum_xx -> ws atomics
//   2. particle_kernel: per-block P (Silverman bandwidth * localized emp cov)
//      in LDS, then per-particle H,S,Chol,Sinv,K (f64); writes covs_post into
//      covs[m=0] slice + 28-float pack per particle into ws
//   3. fused_kernel: Bresenham-interleaved block roles
//      - update blocks  (f32): pts + logw per (m,n)
//      - replicate blocks: covs[m=0] -> 32 mask-selected slices (pure BW)

#define NDIM 6
#define MDIM 3

__global__ __launch_bounds__(256) void stats_kernel(const float* __restrict__ means,
                                                    int N, double* __restrict__ stats) {
    double sx[6];
    double sxx[21];
#pragma unroll
    for (int i = 0; i < 6; ++i) sx[i] = 0.0;
#pragma unroll
    for (int i = 0; i < 21; ++i) sxx[i] = 0.0;

    int stride = gridDim.x * blockDim.x;
    for (int n = blockIdx.x * blockDim.x + threadIdx.x; n < N; n += stride) {
        const float2* mp = (const float2*)(means + (size_t)n * 6);
        float2 a = mp[0], b = mp[1], c = mp[2];
        double x[6] = {a.x, a.y, b.x, b.y, c.x, c.y};
        int p = 0;
#pragma unroll
        for (int i = 0; i < 6; ++i) {
            sx[i] += x[i];
#pragma unroll
            for (int j = i; j < 6; ++j) sxx[p++] += x[i] * x[j];
        }
    }
#pragma unroll
    for (int off = 32; off >= 1; off >>= 1) {
#pragma unroll
        for (int i = 0; i < 6; ++i) sx[i] += __shfl_down(sx[i], off);
#pragma unroll
        for (int i = 0; i < 21; ++i) sxx[i] += __shfl_down(sxx[i], off);
    }
    __shared__ double lds[4][27];
    int wave = threadIdx.x >> 6;
    if ((threadIdx.x & 63) == 0) {
#pragma unroll
        for (int i = 0; i < 6; ++i) lds[wave][i] = sx[i];
#pragma unroll
        for (int i = 0; i < 21; ++i) lds[wave][6 + i] = sxx[i];
    }
    __syncthreads();
    if (threadIdx.x < 27) {
        double v = lds[0][threadIdx.x] + lds[1][threadIdx.x] +
                   lds[2][threadIdx.x] + lds[3][threadIdx.x];
        atomicAdd(&stats[threadIdx.x], v);
    }
}

struct Common {
    double x[6];
    double hx[3];
    double H[3][3];
    double L00, L10, L11, L20, L21, L22, logdet;
    double K[6][3];
};

__device__ __forceinline__ void compute_common(const float* __restrict__ means,
                                               const double* __restrict__ Pws,
                                               const float* __restrict__ Rin,
                                               int n, Common& c) {
    const float2* mp = (const float2*)(means + (size_t)n * 6);
    float2 ma = mp[0], mb = mp[1], mc = mp[2];
    c.x[0] = ma.x; c.x[1] = ma.y; c.x[2] = mb.x;
    c.x[3] = mb.y; c.x[4] = mc.x; c.x[5] = mc.y;
    double px = c.x[0], py = c.x[1], pz = c.x[2];
    double s2 = px * px + py * py;
    double r2 = s2 + pz * pz;
    double rho = sqrt(r2);
    double s = sqrt(s2);
    c.hx[0] = rho;
    c.hx[1] = atan2(py, px);
    c.hx[2] = asin(pz / rho);
    c.H[0][0] = px / rho; c.H[0][1] = py / rho; c.H[0][2] = pz / rho;
    c.H[1][0] = -py / s2; c.H[1][1] = px / s2;  c.H[1][2] = 0.0;
    double invr2s = 1.0 / (r2 * s);
    c.H[2][0] = -pz * px * invr2s; c.H[2][1] = -pz * py * invr2s; c.H[2][2] = s / r2;

    // S = H * P[0:3,0:3] * H^T + R
    double T[3][3];
#pragma unroll
    for (int i = 0; i < 3; ++i)
#pragma unroll
        for (int k = 0; k < 3; ++k)
            T[i][k] = c.H[i][0] * Pws[0 * 6 + k] + c.H[i][1] * Pws[1 * 6 + k] +
                      c.H[i][2] * Pws[2 * 6 + k];
    double S[3][3];
#pragma unroll
    for (int i = 0; i < 3; ++i)
#pragma unroll
        for (int l = 0; l < 3; ++l)
            S[i][l] = T[i][0] * c.H[l][0] + T[i][1] * c.H[l][1] + T[i][2] * c.H[l][2] +
                      (double)Rin[i * 3 + l];

    c.L00 = sqrt(S[0][0]);
    c.L10 = S[1][0] / c.L00;
    c.L20 = S[2][0] / c.L00;
    c.L11 = sqrt(S[1][1] - c.L10 * c.L10);
    c.L21 = (S[2][1] - c.L20 * c.L10) / c.L11;
    c.L22 = sqrt(S[2][2] - c.L20 * c.L20 - c.L21 * c.L21);
    c.logdet = log(c.L00) + log(c.L11) + log(c.L22);

    double a00 = S[0][0], a01 = S[0][1], a02 = S[0][2];
    double a11 = S[1][1], a12 = S[1][2], a22 = S[2][2];
    double c00 = a11 * a22 - a12 * a12;
    double c01 = a02 * a12 - a01 * a22;
    double c02 = a01 * a12 - a02 * a11;
    double c11 = a00 * a22 - a02 * a02;
    double c12 = a01 * a02 - a00 * a12;
    double c22 = a00 * a11 - a01 * a01;
    double det = a00 * c00 + a01 * c01 + a02 * c02;
    double invdet = 1.0 / det;
    double Si[3][3] = {{c00 * invdet, c01 * invdet, c02 * invdet},
                       {c01 * invdet, c11 * invdet, c12 * invdet},
                       {c02 * invdet, c12 * invdet, c22 * invdet}};

#pragma unroll
    for (int i = 0; i < 6; ++i) {
        double pht[3];
#pragma unroll
        for (int k = 0; k < 3; ++k)
            pht[k] = Pws[i * 6 + 0] * c.H[k][0] + Pws[i * 6 + 1] * c.H[k][1] +
                     Pws[i * 6 + 2] * c.H[k][2];
#pragma unroll
        for (int l = 0; l < 3; ++l)
            c.K[i][l] = pht[0] * Si[0][l] + pht[1] * Si[1][l] + pht[2] * Si[2][l];
    }
}

// Computes P per block (in LDS) from global stats, then per-particle work.
__global__ __launch_bounds__(256) void particle_kernel(const float* __restrict__ means,
                                                       const float* __restrict__ Rin,
                                                       const double* __restrict__ stats,
                                                       float* __restrict__ covs0,
                                                       float* __restrict__ pack,
                                                       int N) {
    __shared__ double sP[36];
    if (threadIdx.x == 0) {
        double mean[6];
#pragma unroll
        for (int i = 0; i < 6; ++i) mean[i] = stats[i] / (double)N;
        double bandwidth = pow(4.0 / ((double)N * 8.0), 0.2);  // (4/(n(d+2)))^(2/(d+4)), d=6
        int p = 0;
        for (int i = 0; i < 6; ++i) {
            for (int j = i; j < 6; ++j) {
                double emp = (stats[6 + p] - (double)N * mean[i] * mean[j]) / (double)(N - 1);
                double dd = (double)(j - i);
                double rl = exp(-(dd * dd) / 18.0);  // L = 3.0
                double val = bandwidth * emp * rl;
                sP[i * 6 + j] = val;
                sP[j * 6 + i] = val;
                ++p;
            }
        }
    }
    __syncthreads();

    int n = blockIdx.x * blockDim.x + threadIdx.x;
    if (n >= N) return;
    Common c;
    compute_common(means, sP, Rin, n, c);

    double KH[6][3];
#pragma unroll
    for (int i = 0; i < 6; ++i)
#pragma unroll
        for (int j = 0; j < 3; ++j)
            KH[i][j] = c.K[i][0] * c.H[0][j] + c.K[i][1] * c.H[1][j] + c.K[i][2] * c.H[2][j];

    float cp[36];
#pragma unroll
    for (int i = 0; i < 6; ++i)
#pragma unroll
        for (int j = 0; j < 6; ++j)
            cp[i * 6 + j] = (float)(sP[i * 6 + j] -
                                    (KH[i][0] * sP[0 * 6 + j] +
                                     KH[i][1] * sP[1 * 6 + j] +
                                     KH[i][2] * sP[2 * 6 + j]));
    float4* dst = (float4*)(covs0 + (size_t)n * 36);
#pragma unroll
    for (int q = 0; q < 9; ++q)
        dst[q] = make_float4(cp[q * 4 + 0], cp[q * 4 + 1], cp[q * 4 + 2], cp[q * 4 + 3]);

    if (pack != nullptr) {
        float pk[28];
        pk[0] = (float)c.hx[0]; pk[1] = (float)c.hx[1]; pk[2] = (float)c.hx[2];
        pk[3] = (float)c.logdet;
        pk[4] = (float)c.L00; pk[5] = (float)c.L10; pk[6] = (float)c.L11;
        pk[7] = (float)c.L20; pk[8] = (float)c.L21; pk[9] = (float)c.L22;
#pragma unroll
        for (int i = 0; i < 6; ++i)
#pragma unroll
            for (int l = 0; l < 3; ++l) pk[10 + i * 3 + l] = (float)c.K[i][l];
        float4* pd = (float4*)(pack + (size_t)n * 28);
#pragma unroll
        for (int q = 0; q < 7; ++q)
            pd[q] = make_float4(pk[q * 4 + 0], pk[q * 4 + 1], pk[q * 4 + 2], pk[q * 4 + 3]);
    }
}

__device__ __forceinline__ bool mask_true(const int* m32, const unsigned char* m8, int m) {
    // Defensive: true under either int32 or byte storage for the all-true test mask.
    return (m32[m] != 0) || (m8[m] != 0);
}

// Fused: update (f32) + replicate, Bresenham-interleaved block roles so the
// pure-bandwidth replicate overlaps the compute-heavy update.
__global__ __launch_bounds__(256) void fused_kernel(const float* __restrict__ means,
                                                    const float* __restrict__ meas,
                                                    const int* __restrict__ mask32,
                                                    const unsigned char* __restrict__ mask8,
                                                    const float* __restrict__ pack,
                                                    float* __restrict__ pts,
                                                    float* __restrict__ logw,
                                                    float* __restrict__ covs,
                                                    int N, int M, int blocksPerM,
                                                    int totalBlocks, int blocksR) {
    int b = blockIdx.x;
    int before = (int)(((long long)b * blocksR) / totalBlocks);
    int after = (int)(((long long)(b + 1) * blocksR) / totalBlocks);
    if (after > before) {
        // ---- replicate role (block index 'before' among replicate blocks) ----
        int idx = before * 256 + (int)threadIdx.x;
        int total4 = N * 9;  // float4s per m-slice
        if (idx >= total4) return;
        float4* base = (float4*)covs;
        float4 v = base[idx];  // staging in the m=0 slice (written by particle_kernel)
        float4 z = make_float4(0.f, 0.f, 0.f, 0.f);
        for (int m = 0; m < M; ++m) {
            bool mk = mask_true(mask32, mask8, m);
            base[(size_t)m * total4 + idx] = mk ? v : z;
        }
    } else {
        // ---- update role ----
        int u = b - before;
        int m = u / blocksPerM;
        int nb = u - m * blocksPerM;
        int n = nb * 256 + (int)threadIdx.x;
        if (n >= N) return;
        size_t t = (size_t)m * N + n;
        float2* pp = (float2*)(pts + t * 6);
        if (!mask_true(mask32, mask8, m)) {
            float2 z2 = make_float2(0.f, 0.f);
            pp[0] = z2; pp[1] = z2; pp[2] = z2;
            logw[t] = -INFINITY;
            return;
        }
        const float4* pk4 = (const float4*)(pack + (size_t)n * 28);
        float4 q0 = pk4[0], q1 = pk4[1], q2 = pk4[2], q3 = pk4[3];
        float4 q4 = pk4[4], q5 = pk4[5], q6 = pk4[6];
        float hx0 = q0.x, hx1 = q0.y, hx2 = q0.z, logdet = q0.w;
        float L00 = q1.x, L10 = q1.y, L11 = q1.z, L20 = q1.w;
        float L21 = q2.x, L22 = q2.y;
        float K[18] = {q2.z, q2.w, q3.x, q3.y, q3.z, q3.w,
                       q4.x, q4.y, q4.z, q4.w, q5.x, q5.y,
                       q5.z, q5.w, q6.x, q6.y, q6.z, q6.w};

        float z0 = meas[m * 3 + 0];
        float z1 = meas[m * 3 + 1];
        float z2v = meas[m * 3 + 2];
        float i0 = hx0 - z0, i1 = hx1 - z1, i2 = hx2 - z2v;

        const float2* mm = (const float2*)(means + (size_t)n * 6);
        float2 ma = mm[0], mb = mm[1], mc = mm[2];
        float x[6] = {ma.x, ma.y, mb.x, mb.y, mc.x, mc.y};
        float pt[6];
#pragma unroll
        for (int d = 0; d < 6; ++d)
            pt[d] = x[d] - (K[d * 3 + 0] * i0 + K[d * 3 + 1] * i1 + K[d * 3 + 2] * i2);
        pp[0] = make_float2(pt[0], pt[1]);
        pp[1] = make_float2(pt[2], pt[3]);
        pp[2] = make_float2(pt[4], pt[5]);

        float px = pt[0], py = pt[1], pz = pt[2];
        float r2 = px * px + py * py + pz * pz;
        float rho = sqrtf(r2);
        float d0 = z0 - rho;
        float d1 = z1 - atan2f(py, px);
        float d2 = z2v - asinf(pz / rho);
        float y0 = d0 / L00;
        float y1 = (d1 - L10 * y0) / L11;
        float y2 = (d2 - L20 * y0 - L21 * y1) / L22;
        float quad = y0 * y0 + y1 * y1 + y2 * y2;
        logw[t] = -0.5f * quad - logdet - 2.7568156f;  // 0.5*3*log(2*pi)
    }
}

// ---- Fallback path (ws too small for the pack): recompute per (m,n) in f64 ----
__global__ __launch_bounds__(256) void update_recompute_kernel(const float* __restrict__ means,
                                                               const float* __restrict__ meas,
                                                               const int* __restrict__ mask32,
                                                               const unsigned char* __restrict__ mask8,
                                                               const float* __restrict__ Rin,
                                                               const double* __restrict__ stats,
                                                               float* __restrict__ pts,
                                                               float* __restrict__ logw,
                                                               int N, int M) {
    __shared__ double sP[36];
    if (threadIdx.x == 0) {
        double mean[6];
#pragma unroll
        for (int i = 0; i < 6; ++i) mean[i] = stats[i] / (double)N;
        double bandwidth = pow(4.0 / ((double)N * 8.0), 0.2);
        int p = 0;
        for (int i = 0; i < 6; ++i) {
            for (int j = i; j < 6; ++j) {
                double emp = (stats[6 + p] - (double)N * mean[i] * mean[j]) / (double)(N - 1);
                double dd = (double)(j - i);
                double val = bandwidth * emp * exp(-(dd * dd) / 18.0);
                sP[i * 6 + j] = val;
                sP[j * 6 + i] = val;
                ++p;
            }
        }
    }
    __syncthreads();
    int t = blockIdx.x * blockDim.x + threadIdx.x;
    if (t >= M * N) return;
    int m = t / N;
    int n = t - m * N;
    float2* pp = (float2*)(pts + (size_t)t * 6);
    if (!mask_true(mask32, mask8, m)) {
        float2 z2 = make_float2(0.f, 0.f);
        pp[0] = z2; pp[1] = z2; pp[2] = z2;
        logw[t] = -INFINITY;
        return;
    }
    Common c;
    compute_common(means, sP, Rin, n, c);
    double z0 = (double)meas[m * 3 + 0];
    double z1 = (double)meas[m * 3 + 1];
    double z2v = (double)meas[m * 3 + 2];
    double i0 = c.hx[0] - z0, i1 = c.hx[1] - z1, i2 = c.hx[2] - z2v;
    double pt[6];
#pragma unroll
    for (int d = 0; d < 6; ++d)
        pt[d] = c.x[d] - (c.K[d][0] * i0 + c.K[d][1] * i1 + c.K[d][2] * i2);
    pp[0] = make_float2((float)pt[0], (float)pt[1]);
    pp[1] = make_float2((float)pt[2], (float)pt[3]);
    pp[2] = make_float2((float)pt[4], (float)pt[5]);
    double px = pt[0], py = pt[1], pz = pt[2];
    double rho = sqrt(px * px + py * py + pz * pz);
    double d0 = z0 - rho, d1 = z1 - atan2(py, px), d2 = z2v - asin(pz / rho);
    double y0 = d0 / c.L00;
    double y1 = (d1 - c.L10 * y0) / c.L11;
    double y2 = (d2 - c.L20 * y0 - c.L21 * y1) / c.L22;
    logw[t] = (float)(-0.5 * (y0 * y0 + y1 * y1 + y2 * y2) - c.logdet - 2.7568155996140185);
}

__global__ __launch_bounds__(256) void replicate_kernel(float* __restrict__ covs,
                                                        const int* __restrict__ mask32,
                                                        const unsigned char* __restrict__ mask8,
                                                        int N, int M) {
    int idx = blockIdx.x * blockDim.x + threadIdx.x;
    int total = N * 9;
    if (idx >= total) return;
    float4* base = (float4*)covs;
    float4 v = base[idx];
    float4 z = make_float4(0.f, 0.f, 0.f, 0.f);
    for (int m = 0; m < M; ++m) {
        bool mk = mask_true(mask32, mask8, m);
        base[(size_t)m * total + idx] = mk ? v : z;
    }
}

extern "C" void kernel_launch(void* const* d_in, const int* in_sizes, int n_in,
                              void* d_out, int out_size, void* d_ws, size_t ws_size,
                              hipStream_t stream) {
    const float* means = (const float*)d_in[0];
    const float* meas = (const float*)d_in[3];
    const int* mask32 = (const int*)d_in[4];
    const unsigned char* mask8 = (const unsigned char*)d_in[4];
    const float* Rin = (const float*)d_in[5];

    int N = in_sizes[0] / NDIM;
    int M = in_sizes[3] / MDIM;

    float* out = (float*)d_out;
    float* pts = out;                               // [M,N,6]
    float* logw = out + (size_t)M * N * 6;          // [M,N]
    float* covs = out + (size_t)M * N * 7;          // [M,N,6,6]

    double* ws = (double*)d_ws;
    double* stats = ws;          // 27 doubles used
    float* pack = (float*)(ws + 32);
    size_t need = 32 * sizeof(double) + (size_t)N * 28 * sizeof(float);
    bool use_pack = (ws_size >= need);

    hipMemsetAsync(d_ws, 0, 27 * sizeof(double), stream);

    stats_kernel<<<128, 256, 0, stream>>>(means, N, stats);

    int blocksPerM = (N + 255) / 256;
    particle_kernel<<<blocksPerM, 256, 0, stream>>>(means, Rin, stats, covs,
                                                    use_pack ? pack : nullptr, N);
    if (use_pack) {
        int blocksU = M * blocksPerM;
        int blocksR = (N * 9 + 255) / 256;
        int totalBlocks = blocksU + blocksR;
        fused_kernel<<<totalBlocks, 256, 0, stream>>>(means, meas, mask32, mask8, pack,
                                                      pts, logw, covs, N, M, blocksPerM,
                                                      totalBlocks, blocksR);
    } else {
        int totalMN = M * N;
        update_recompute_kernel<<<(totalMN + 255) / 256, 256, 0, stream>>>(
            means, meas, mask32, mask8, Rin, stats, pts, logw, N, M);
        replicate_kernel<<<(N * 9 + 255) / 256, 256, 0, stream>>>(covs, mask32, mask8, N, M);
    }
}

// Round 3
// 86.058 us; speedup vs baseline: 1.3846x; 1.3846x over previous
//
#include <hip/hip_runtime.h>
#include <math.h>

// EnGMPHD update kernel for MI355X (round 3).
// See header comments in previous rounds. Pipeline (path A):
//   memset stats -> stats_kernel -> particle_kernel (stage+pack in ws)
//   -> fused_out_kernel (all 275 MB of output bytes, nt stores).

#define NDIM 6
#define MDIM 3
typedef float f32x4 __attribute__((ext_vector_type(4)));

__device__ __forceinline__ bool mask_true(const int* m32, const unsigned char* m8, int m) {
    return (m32[m] != 0) || (m8[m] != 0);
}

__global__ __launch_bounds__(256) void stats_kernel(const float* __restrict__ means,
                                                    int N, double* __restrict__ stats) {
    double sx[6];
    double sxx[21];
#pragma unroll
    for (int i = 0; i < 6; ++i) sx[i] = 0.0;
#pragma unroll
    for (int i = 0; i < 21; ++i) sxx[i] = 0.0;

    int stride = gridDim.x * blockDim.x;
    for (int n = blockIdx.x * blockDim.x + threadIdx.x; n < N; n += stride) {
        const float2* mp = (const float2*)(means + (size_t)n * 6);
        float2 a = mp[0], b = mp[1], c = mp[2];
        double x[6] = {a.x, a.y, b.x, b.y, c.x, c.y};
        int p = 0;
#pragma unroll
        for (int i = 0; i < 6; ++i) {
            sx[i] += x[i];
#pragma unroll
            for (int j = i; j < 6; ++j) sxx[p++] += x[i] * x[j];
        }
    }
#pragma unroll
    for (int off = 32; off >= 1; off >>= 1) {
#pragma unroll
        for (int i = 0; i < 6; ++i) sx[i] += __shfl_down(sx[i], off);
#pragma unroll
        for (int i = 0; i < 21; ++i) sxx[i] += __shfl_down(sxx[i], off);
    }
    __shared__ double lds[4][27];
    int wave = threadIdx.x >> 6;
    if ((threadIdx.x & 63) == 0) {
#pragma unroll
        for (int i = 0; i < 6; ++i) lds[wave][i] = sx[i];
#pragma unroll
        for (int i = 0; i < 21; ++i) lds[wave][6 + i] = sxx[i];
    }
    __syncthreads();
    if (threadIdx.x < 27) {
        double v = lds[0][threadIdx.x] + lds[1][threadIdx.x] +
                   lds[2][threadIdx.x] + lds[3][threadIdx.x];
        atomicAdd(&stats[threadIdx.x], v);
    }
}

__device__ __forceinline__ void build_P(const double* __restrict__ stats, int N,
                                        double* __restrict__ sP) {
    double mean[6];
#pragma unroll
    for (int i = 0; i < 6; ++i) mean[i] = stats[i] / (double)N;
    double bandwidth = pow(4.0 / ((double)N * 8.0), 0.2);  // (4/(n(d+2)))^(2/(d+4)), d=6
    int p = 0;
    for (int i = 0; i < 6; ++i) {
        for (int j = i; j < 6; ++j) {
            double emp = (stats[6 + p] - (double)N * mean[i] * mean[j]) / (double)(N - 1);
            double dd = (double)(j - i);
            double val = bandwidth * emp * exp(-(dd * dd) / 18.0);  // L = 3.0
            sP[i * 6 + j] = val;
            sP[j * 6 + i] = val;
            ++p;
        }
    }
}

// Per-particle precompute. f32 transcendentals; f64 for S/Chol/Sinv/K algebra.
// Writes covs_post to `stage` ([N,36]) and the 28-float pack to `pack`.
__global__ __launch_bounds__(256) void particle_kernel(const float* __restrict__ means,
                                                       const float* __restrict__ Rin,
                                                       const double* __restrict__ stats,
                                                       float* __restrict__ stage,
                                                       float* __restrict__ pack,
                                                       int N) {
    __shared__ double sP[36];
    __shared__ float sPf[36];
    if (threadIdx.x == 0) build_P(stats, N, sP);
    __syncthreads();
    if (threadIdx.x < 36) sPf[threadIdx.x] = (float)sP[threadIdx.x];
    __syncthreads();

    int n = blockIdx.x * blockDim.x + threadIdx.x;
    if (n >= N) return;

    const float2* mp = (const float2*)(means + (size_t)n * 6);
    float2 ma = mp[0], mb = mp[1];
    float px = ma.x, py = ma.y, pz = mb.x;
    float s2 = px * px + py * py;
    float r2 = s2 + pz * pz;
    float rho = sqrtf(r2);
    float s = sqrtf(s2);
    float hx0 = rho;
    float hx1 = atan2f(py, px);
    float hx2 = asinf(pz / rho);
    float H[3][3];
    H[0][0] = px / rho; H[0][1] = py / rho; H[0][2] = pz / rho;
    H[1][0] = -py / s2; H[1][1] = px / s2;  H[1][2] = 0.0f;
    float invr2s = 1.0f / (r2 * s);
    H[2][0] = -pz * px * invr2s; H[2][1] = -pz * py * invr2s; H[2][2] = s / r2;

    double T[3][3];
#pragma unroll
    for (int i = 0; i < 3; ++i)
#pragma unroll
        for (int k = 0; k < 3; ++k)
            T[i][k] = (double)H[i][0] * sP[0 * 6 + k] + (double)H[i][1] * sP[1 * 6 + k] +
                      (double)H[i][2] * sP[2 * 6 + k];
    double S[3][3];
#pragma unroll
    for (int i = 0; i < 3; ++i)
#pragma unroll
        for (int l = 0; l < 3; ++l)
            S[i][l] = T[i][0] * (double)H[l][0] + T[i][1] * (double)H[l][1] +
                      T[i][2] * (double)H[l][2] + (double)Rin[i * 3 + l];

    double L00 = sqrt(S[0][0]);
    double L10 = S[1][0] / L00;
    double L20 = S[2][0] / L00;
    double L11 = sqrt(S[1][1] - L10 * L10);
    double L21 = (S[2][1] - L20 * L10) / L11;
    double L22 = sqrt(S[2][2] - L20 * L20 - L21 * L21);
    float logdet = logf((float)(L00 * L11 * L22));

    double a00 = S[0][0], a01 = S[0][1], a02 = S[0][2];
    double a11 = S[1][1], a12 = S[1][2], a22 = S[2][2];
    double c00 = a11 * a22 - a12 * a12;
    double c01 = a02 * a12 - a01 * a22;
    double c02 = a01 * a12 - a02 * a11;
    double c11 = a00 * a22 - a02 * a02;
    double c12 = a01 * a02 - a00 * a12;
    double c22 = a00 * a11 - a01 * a01;
    double invdet = 1.0 / (a00 * c00 + a01 * c01 + a02 * c02);
    double Si[3][3] = {{c00 * invdet, c01 * invdet, c02 * invdet},
                       {c01 * invdet, c11 * invdet, c12 * invdet},
                       {c02 * invdet, c12 * invdet, c22 * invdet}};

    float Kf[6][3];
#pragma unroll
    for (int i = 0; i < 6; ++i) {
        double pht[3];
#pragma unroll
        for (int k = 0; k < 3; ++k)
            pht[k] = sP[i * 6 + 0] * (double)H[k][0] + sP[i * 6 + 1] * (double)H[k][1] +
                     sP[i * 6 + 2] * (double)H[k][2];
#pragma unroll
        for (int l = 0; l < 3; ++l)
            Kf[i][l] = (float)(pht[0] * Si[0][l] + pht[1] * Si[1][l] + pht[2] * Si[2][l]);
    }

    float KH[6][3];
#pragma unroll
    for (int i = 0; i < 6; ++i)
#pragma unroll
        for (int j = 0; j < 3; ++j)
            KH[i][j] = Kf[i][0] * H[0][j] + Kf[i][1] * H[1][j] + Kf[i][2] * H[2][j];
    float cp[36];
#pragma unroll
    for (int i = 0; i < 6; ++i)
#pragma unroll
        for (int j = 0; j < 6; ++j)
            cp[i * 6 + j] = sPf[i * 6 + j] - (KH[i][0] * sPf[0 * 6 + j] +
                                              KH[i][1] * sPf[1 * 6 + j] +
                                              KH[i][2] * sPf[2 * 6 + j]);
    f32x4* dst = (f32x4*)(stage + (size_t)n * 36);
#pragma unroll
    for (int q = 0; q < 9; ++q) {
        f32x4 v = {cp[q * 4 + 0], cp[q * 4 + 1], cp[q * 4 + 2], cp[q * 4 + 3]};
        dst[q] = v;
    }

    float pk[28];
    pk[0] = hx0; pk[1] = hx1; pk[2] = hx2; pk[3] = logdet;
    pk[4] = (float)L00; pk[5] = (float)L10; pk[6] = (float)L11;
    pk[7] = (float)L20; pk[8] = (float)L21; pk[9] = (float)L22;
#pragma unroll
    for (int i = 0; i < 6; ++i)
#pragma unroll
        for (int l = 0; l < 3; ++l) pk[10 + i * 3 + l] = Kf[i][l];
    f32x4* pd = (f32x4*)(pack + (size_t)n * 28);
#pragma unroll
    for (int q = 0; q < 7; ++q) {
        f32x4 v = {pk[q * 4 + 0], pk[q * 4 + 1], pk[q * 4 + 2], pk[q * 4 + 3]};
        pd[q] = v;
    }
}

// One kernel for ALL output bytes. grid = (UB + RB, M).
//   x <  UB : update role — pts (LDS repack -> nt float4) + logw
//   x >= UB : replicate role — 4 contiguous nt float4 per thread from stage
__global__ __launch_bounds__(256) void fused_out_kernel(const float* __restrict__ means,
                                                        const float* __restrict__ meas,
                                                        const int* __restrict__ mask32,
                                                        const unsigned char* __restrict__ mask8,
                                                        const float* __restrict__ pack,
                                                        const float* __restrict__ stage,
                                                        float* __restrict__ pts,
                                                        float* __restrict__ logw,
                                                        float* __restrict__ covs,
                                                        int N, int UB, int doRep) {
    __shared__ float spts[6 * 256];
    int m = blockIdx.y;
    bool mk = mask_true(mask32, mask8, m);

    if ((int)blockIdx.x >= UB) {
        if (!doRep) return;
        int total4 = N * 9;
        const f32x4* s4 = (const f32x4*)stage;
        f32x4* d4 = (f32x4*)covs + (size_t)m * total4;
        int i0 = ((int)blockIdx.x - UB) * 1024 + (int)threadIdx.x;
        f32x4 z = {0.f, 0.f, 0.f, 0.f};
#pragma unroll
        for (int k = 0; k < 4; ++k) {
            int i = i0 + k * 256;
            if (i < total4) {
                f32x4 v = mk ? s4[i] : z;
                __builtin_nontemporal_store(v, d4 + i);
            }
        }
        return;
    }

    int nb = blockIdx.x;
    int nloc = threadIdx.x;
    int n = nb * 256 + nloc;
    int count = N - nb * 256;
    if (count > 256) count = 256;

    if (nloc < count) {
        float pt[6];
        if (mk) {
            const f32x4* pk4 = (const f32x4*)(pack + (size_t)n * 28);
            f32x4 q0 = pk4[0], q1 = pk4[1], q2 = pk4[2], q3 = pk4[3];
            f32x4 q4 = pk4[4], q5 = pk4[5], q6 = pk4[6];
            float hx0 = q0.x, hx1 = q0.y, hx2 = q0.z, logdet = q0.w;
            float L00 = q1.x, L10 = q1.y, L11 = q1.z, L20 = q1.w;
            float L21 = q2.x, L22 = q2.y;
            float K[18] = {q2.z, q2.w, q3.x, q3.y, q3.z, q3.w,
                           q4.x, q4.y, q4.z, q4.w, q5.x, q5.y,
                           q5.z, q5.w, q6.x, q6.y, q6.z, q6.w};

            float z0 = meas[m * 3 + 0];
            float z1 = meas[m * 3 + 1];
            float z2v = meas[m * 3 + 2];
            float i0 = hx0 - z0, i1 = hx1 - z1, i2 = hx2 - z2v;

            const float2* mm = (const float2*)(means + (size_t)n * 6);
            float2 ma = mm[0], mb = mm[1], mc = mm[2];
            float x[6] = {ma.x, ma.y, mb.x, mb.y, mc.x, mc.y};
#pragma unroll
            for (int d = 0; d < 6; ++d)
                pt[d] = x[d] - (K[d * 3 + 0] * i0 + K[d * 3 + 1] * i1 + K[d * 3 + 2] * i2);

            float px = pt[0], py = pt[1], pz = pt[2];
            float r2 = px * px + py * py + pz * pz;
            float rho = sqrtf(r2);
            float d0 = z0 - rho;
            float d1 = z1 - atan2f(py, px);
            float d2 = z2v - asinf(pz / rho);
            float y0 = d0 / L00;
            float y1 = (d1 - L10 * y0) / L11;
            float y2 = (d2 - L20 * y0 - L21 * y1) / L22;
            float quad = y0 * y0 + y1 * y1 + y2 * y2;
            logw[(size_t)m * N + n] = -0.5f * quad - logdet - 2.7568156f;  // 1.5*log(2pi)
        } else {
#pragma unroll
            for (int d = 0; d < 6; ++d) pt[d] = 0.f;
            logw[(size_t)m * N + n] = -INFINITY;
        }
#pragma unroll
        for (int d = 0; d < 6; ++d) spts[nloc * 6 + d] = pt[d];
    }
    __syncthreads();

    int nf = count * 6;
    float* dst = pts + ((size_t)m * N + (size_t)nb * 256) * 6;
    const f32x4* s4 = (const f32x4*)spts;
    f32x4* d4 = (f32x4*)dst;
    int n4 = nf >> 2;
    for (int i = threadIdx.x; i < n4; i += 256)
        __builtin_nontemporal_store(s4[i], d4 + i);
    for (int i = (n4 << 2) + (int)threadIdx.x; i < nf; i += 256)
        dst[i] = spts[i];
}

// Per-thread read-then-loop-write replicate (race-free when stage == covs slice 0).
__global__ __launch_bounds__(256) void replicate_loop_kernel(const float* __restrict__ stage,
                                                             float* __restrict__ covs,
                                                             const int* __restrict__ mask32,
                                                             const unsigned char* __restrict__ mask8,
                                                             int N, int M) {
    int idx = blockIdx.x * blockDim.x + threadIdx.x;
    int total4 = N * 9;
    if (idx >= total4) return;
    const f32x4* s4 = (const f32x4*)stage;
    f32x4* base = (f32x4*)covs;
    f32x4 v = s4[idx];
    f32x4 z = {0.f, 0.f, 0.f, 0.f};
    for (int m = 0; m < M; ++m) {
        bool mk = mask_true(mask32, mask8, m);
        __builtin_nontemporal_store(mk ? v : z, base + (size_t)m * total4 + idx);
    }
}

extern "C" void kernel_launch(void* const* d_in, const int* in_sizes, int n_in,
                              void* d_out, int out_size, void* d_ws, size_t ws_size,
                              hipStream_t stream) {
    const float* means = (const float*)d_in[0];
    const float* meas = (const float*)d_in[3];
    const int* mask32 = (const int*)d_in[4];
    const unsigned char* mask8 = (const unsigned char*)d_in[4];
    const float* Rin = (const float*)d_in[5];

    int N = in_sizes[0] / NDIM;
    int M = in_sizes[3] / MDIM;

    float* out = (float*)d_out;
    float* pts = out;                               // [M,N,6]
    float* logw = out + (size_t)M * N * 6;          // [M,N]
    float* covs = out + (size_t)M * N * 7;          // [M,N,6,6]

    double* ws = (double*)d_ws;
    double* stats = ws;                     // 27 f64
    float* pack = (float*)(ws + 32);        // N*28 f32
    float* stage = pack + (size_t)N * 28;   // N*36 f32
    size_t need_pack = 32 * sizeof(double) + (size_t)N * 28 * sizeof(float);
    size_t need_full = need_pack + (size_t)N * 36 * sizeof(float);

    hipMemsetAsync(d_ws, 0, 27 * sizeof(double), stream);
    stats_kernel<<<128, 256, 0, stream>>>(means, N, stats);

    int blocksPerM = (N + 255) / 256;

    if (ws_size >= need_full) {
        // Path A: stage in ws; one kernel emits all 275 MB of output.
        particle_kernel<<<blocksPerM, 256, 0, stream>>>(means, Rin, stats, stage, pack, N);
        int RB = (N * 9 + 1023) / 1024;
        dim3 grid(blocksPerM + RB, M);
        fused_out_kernel<<<grid, 256, 0, stream>>>(means, meas, mask32, mask8, pack,
                                                   stage, pts, logw, covs, N, blocksPerM, 1);
    } else {
        // Path B: stage in covs slice 0; update-only fused kernel + loop replicate.
        particle_kernel<<<blocksPerM, 256, 0, stream>>>(means, Rin, stats, covs, pack, N);
        dim3 gridU(blocksPerM, M);
        fused_out_kernel<<<gridU, 256, 0, stream>>>(means, meas, mask32, mask8, pack,
                                                    covs, pts, logw, covs, N, blocksPerM, 0);
        replicate_loop_kernel<<<(N * 9 + 255) / 256, 256, 0, stream>>>(covs, covs, mask32,
                                                                       mask8, N, M);
    }
}

// Round 4
// 81.693 us; speedup vs baseline: 1.4586x; 1.0534x over previous
//
#include <hip/hip_runtime.h>
#include <math.h>

// EnGMPHD update kernel for MI355X (round 4).
// Pipeline (path A):
//   1. stats_partial_kernel: 128 blocks write per-block partial sums (stat-major)
//   2. particle_kernel: reduce partials -> P (LDS); per-particle H/S/Chol/Sinv/K
//      (f32 transcendentals, f64 algebra); stage [N,36] + pack [N,28] in ws
//   3. fused_out_kernel (1D grid, replicate blocks FIRST):
//      - replicate blocks: load 4 float4 of stage ONCE, nt-store to all M slices
//      - update blocks: 4 m's per block; pack read once; pts via LDS repack ->
//        contiguous nt float4; logw nt scalar.

#define NDIM 6
#define MDIM 3
#define NB_STATS 128
#define GROUP_M 4
typedef float f32x4 __attribute__((ext_vector_type(4)));

__device__ __forceinline__ bool mask_true(const int* m32, const unsigned char* m8, int m) {
    return (m32[m] != 0) || (m8[m] != 0);
}

// Per-block partial sums of [sum_x(6), sum_xx_uptri(21)], stat-major:
// partials[stat * NB_STATS + blockIdx.x]. No atomics, no memset needed.
__global__ __launch_bounds__(256) void stats_partial_kernel(const float* __restrict__ means,
                                                            int N, double* __restrict__ partials) {
    double sx[6];
    double sxx[21];
#pragma unroll
    for (int i = 0; i < 6; ++i) sx[i] = 0.0;
#pragma unroll
    for (int i = 0; i < 21; ++i) sxx[i] = 0.0;

    int stride = gridDim.x * blockDim.x;
    for (int n = blockIdx.x * blockDim.x + threadIdx.x; n < N; n += stride) {
        const float2* mp = (const float2*)(means + (size_t)n * 6);
        float2 a = mp[0], b = mp[1], c = mp[2];
        double x[6] = {a.x, a.y, b.x, b.y, c.x, c.y};
        int p = 0;
#pragma unroll
        for (int i = 0; i < 6; ++i) {
            sx[i] += x[i];
#pragma unroll
            for (int j = i; j < 6; ++j) sxx[p++] += x[i] * x[j];
        }
    }
#pragma unroll
    for (int off = 32; off >= 1; off >>= 1) {
#pragma unroll
        for (int i = 0; i < 6; ++i) sx[i] += __shfl_down(sx[i], off);
#pragma unroll
        for (int i = 0; i < 21; ++i) sxx[i] += __shfl_down(sxx[i], off);
    }
    __shared__ double lds[4][27];
    int wave = threadIdx.x >> 6;
    if ((threadIdx.x & 63) == 0) {
#pragma unroll
        for (int i = 0; i < 6; ++i) lds[wave][i] = sx[i];
#pragma unroll
        for (int i = 0; i < 21; ++i) lds[wave][6 + i] = sxx[i];
    }
    __syncthreads();
    if (threadIdx.x < 27) {
        double v = lds[0][threadIdx.x] + lds[1][threadIdx.x] +
                   lds[2][threadIdx.x] + lds[3][threadIdx.x];
        partials[threadIdx.x * NB_STATS + blockIdx.x] = v;
    }
}

// Per-particle precompute. Reduces stats partials per block (threads 0..26,
// contiguous reads), builds P on thread 0, then per-particle work.
__global__ __launch_bounds__(256) void particle_kernel(const float* __restrict__ means,
                                                       const float* __restrict__ Rin,
                                                       const double* __restrict__ partials,
                                                       float* __restrict__ stage,
                                                       float* __restrict__ pack,
                                                       int N) {
    __shared__ double sStats[27];
    __shared__ double sP[36];
    __shared__ float sPf[36];
    if (threadIdx.x < 27) {
        const double* src = partials + (size_t)threadIdx.x * NB_STATS;
        double acc = 0.0;
#pragma unroll 8
        for (int b = 0; b < NB_STATS; ++b) acc += src[b];
        sStats[threadIdx.x] = acc;
    }
    __syncthreads();
    if (threadIdx.x == 0) {
        double mean[6];
#pragma unroll
        for (int i = 0; i < 6; ++i) mean[i] = sStats[i] / (double)N;
        double bandwidth = pow(4.0 / ((double)N * 8.0), 0.2);  // d=6
        int p = 0;
        for (int i = 0; i < 6; ++i) {
            for (int j = i; j < 6; ++j) {
                double emp = (sStats[6 + p] - (double)N * mean[i] * mean[j]) / (double)(N - 1);
                double dd = (double)(j - i);
                double val = bandwidth * emp * exp(-(dd * dd) / 18.0);  // L = 3.0
                sP[i * 6 + j] = val;
                sP[j * 6 + i] = val;
                ++p;
            }
        }
    }
    __syncthreads();
    if (threadIdx.x < 36) sPf[threadIdx.x] = (float)sP[threadIdx.x];
    __syncthreads();

    int n = blockIdx.x * blockDim.x + threadIdx.x;
    if (n >= N) return;

    const float2* mp = (const float2*)(means + (size_t)n * 6);
    float2 ma = mp[0], mb = mp[1];
    float px = ma.x, py = ma.y, pz = mb.x;
    float s2 = px * px + py * py;
    float r2 = s2 + pz * pz;
    float rho = sqrtf(r2);
    float s = sqrtf(s2);
    float hx0 = rho;
    float hx1 = atan2f(py, px);
    float hx2 = asinf(pz / rho);
    float H[3][3];
    H[0][0] = px / rho; H[0][1] = py / rho; H[0][2] = pz / rho;
    H[1][0] = -py / s2; H[1][1] = px / s2;  H[1][2] = 0.0f;
    float invr2s = 1.0f / (r2 * s);
    H[2][0] = -pz * px * invr2s; H[2][1] = -pz * py * invr2s; H[2][2] = s / r2;

    double T[3][3];
#pragma unroll
    for (int i = 0; i < 3; ++i)
#pragma unroll
        for (int k = 0; k < 3; ++k)
            T[i][k] = (double)H[i][0] * sP[0 * 6 + k] + (double)H[i][1] * sP[1 * 6 + k] +
                      (double)H[i][2] * sP[2 * 6 + k];
    double S[3][3];
#pragma unroll
    for (int i = 0; i < 3; ++i)
#pragma unroll
        for (int l = 0; l < 3; ++l)
            S[i][l] = T[i][0] * (double)H[l][0] + T[i][1] * (double)H[l][1] +
                      T[i][2] * (double)H[l][2] + (double)Rin[i * 3 + l];

    double L00 = sqrt(S[0][0]);
    double L10 = S[1][0] / L00;
    double L20 = S[2][0] / L00;
    double L11 = sqrt(S[1][1] - L10 * L10);
    double L21 = (S[2][1] - L20 * L10) / L11;
    double L22 = sqrt(S[2][2] - L20 * L20 - L21 * L21);
    float logdet = logf((float)(L00 * L11 * L22));

    double a00 = S[0][0], a01 = S[0][1], a02 = S[0][2];
    double a11 = S[1][1], a12 = S[1][2], a22 = S[2][2];
    double c00 = a11 * a22 - a12 * a12;
    double c01 = a02 * a12 - a01 * a22;
    double c02 = a01 * a12 - a02 * a11;
    double c11 = a00 * a22 - a02 * a02;
    double c12 = a01 * a02 - a00 * a12;
    double c22 = a00 * a11 - a01 * a01;
    double invdet = 1.0 / (a00 * c00 + a01 * c01 + a02 * c02);
    double Si[3][3] = {{c00 * invdet, c01 * invdet, c02 * invdet},
                       {c01 * invdet, c11 * invdet, c12 * invdet},
                       {c02 * invdet, c12 * invdet, c22 * invdet}};

    float Kf[6][3];
#pragma unroll
    for (int i = 0; i < 6; ++i) {
        double pht[3];
#pragma unroll
        for (int k = 0; k < 3; ++k)
            pht[k] = sP[i * 6 + 0] * (double)H[k][0] + sP[i * 6 + 1] * (double)H[k][1] +
                     sP[i * 6 + 2] * (double)H[k][2];
#pragma unroll
        for (int l = 0; l < 3; ++l)
            Kf[i][l] = (float)(pht[0] * Si[0][l] + pht[1] * Si[1][l] + pht[2] * Si[2][l]);
    }

    float KH[6][3];
#pragma unroll
    for (int i = 0; i < 6; ++i)
#pragma unroll
        for (int j = 0; j < 3; ++j)
            KH[i][j] = Kf[i][0] * H[0][j] + Kf[i][1] * H[1][j] + Kf[i][2] * H[2][j];
    float cp[36];
#pragma unroll
    for (int i = 0; i < 6; ++i)
#pragma unroll
        for (int j = 0; j < 6; ++j)
            cp[i * 6 + j] = sPf[i * 6 + j] - (KH[i][0] * sPf[0 * 6 + j] +
                                              KH[i][1] * sPf[1 * 6 + j] +
                                              KH[i][2] * sPf[2 * 6 + j]);
    f32x4* dst = (f32x4*)(stage + (size_t)n * 36);
#pragma unroll
    for (int q = 0; q < 9; ++q) {
        f32x4 v = {cp[q * 4 + 0], cp[q * 4 + 1], cp[q * 4 + 2], cp[q * 4 + 3]};
        dst[q] = v;
    }

    float pk[28];
    pk[0] = hx0; pk[1] = hx1; pk[2] = hx2; pk[3] = logdet;
    pk[4] = (float)L00; pk[5] = (float)L10; pk[6] = (float)L11;
    pk[7] = (float)L20; pk[8] = (float)L21; pk[9] = (float)L22;
#pragma unroll
    for (int i = 0; i < 6; ++i)
#pragma unroll
        for (int l = 0; l < 3; ++l) pk[10 + i * 3 + l] = Kf[i][l];
    f32x4* pd = (f32x4*)(pack + (size_t)n * 28);
#pragma unroll
    for (int q = 0; q < 7; ++q) {
        f32x4 v = {pk[q * 4 + 0], pk[q * 4 + 1], pk[q * 4 + 2], pk[q * 4 + 3]};
        pd[q] = v;
    }
}

// 1D grid: [0, repBlocks) replicate (read-once, write-M-slices);
// [repBlocks, repBlocks + UBx*MG) update (GROUP_M m's per block).
__global__ __launch_bounds__(256) void fused_out_kernel(const float* __restrict__ means,
                                                        const float* __restrict__ meas,
                                                        const int* __restrict__ mask32,
                                                        const unsigned char* __restrict__ mask8,
                                                        const float* __restrict__ pack,
                                                        const float* __restrict__ stage,
                                                        float* __restrict__ pts,
                                                        float* __restrict__ logw,
                                                        float* __restrict__ covs,
                                                        int N, int M, int RB, int UBx,
                                                        int doRep) {
    __shared__ float spts[6 * 256];
    int b = blockIdx.x;
    int repBlocks = doRep ? RB : 0;

    if (b < repBlocks) {
        // ---- replicate: load chunk once, stream to all M slices ----
        int total4 = N * 9;
        const f32x4* s4 = (const f32x4*)stage;
        f32x4* base = (f32x4*)covs;
        int i0 = b * 1024 + (int)threadIdx.x;
        f32x4 z = {0.f, 0.f, 0.f, 0.f};
        f32x4 v[4];
        int idx[4];
        bool ok[4];
#pragma unroll
        for (int k = 0; k < 4; ++k) {
            idx[k] = i0 + k * 256;
            ok[k] = idx[k] < total4;
            v[k] = ok[k] ? s4[idx[k]] : z;
        }
        for (int m = 0; m < M; ++m) {
            bool mk = mask_true(mask32, mask8, m);
            f32x4* d4 = base + (size_t)m * total4;
#pragma unroll
            for (int k = 0; k < 4; ++k)
                if (ok[k]) __builtin_nontemporal_store(mk ? v[k] : z, d4 + idx[k]);
        }
        return;
    }

    // ---- update: one block handles GROUP_M measurements for 256 particles ----
    int b2 = b - repBlocks;
    int mg = b2 / UBx;
    int nb = b2 - mg * UBx;
    int n0 = nb * 256;
    int count = N - n0;
    if (count > 256) count = 256;
    int nloc = threadIdx.x;
    int n = n0 + nloc;

    float hx0 = 0, hx1 = 0, hx2 = 0, logdet = 0;
    float L00 = 1, L10 = 0, L11 = 1, L20 = 0, L21 = 0, L22 = 1;
    float K[18];
    float x[6];
    if (nloc < count) {
        const f32x4* pk4 = (const f32x4*)(pack + (size_t)n * 28);
        f32x4 q0 = pk4[0], q1 = pk4[1], q2 = pk4[2], q3 = pk4[3];
        f32x4 q4 = pk4[4], q5 = pk4[5], q6 = pk4[6];
        hx0 = q0.x; hx1 = q0.y; hx2 = q0.z; logdet = q0.w;
        L00 = q1.x; L10 = q1.y; L11 = q1.z; L20 = q1.w;
        L21 = q2.x; L22 = q2.y;
        K[0] = q2.z; K[1] = q2.w; K[2] = q3.x; K[3] = q3.y; K[4] = q3.z; K[5] = q3.w;
        K[6] = q4.x; K[7] = q4.y; K[8] = q4.z; K[9] = q4.w; K[10] = q5.x; K[11] = q5.y;
        K[12] = q5.z; K[13] = q5.w; K[14] = q6.x; K[15] = q6.y; K[16] = q6.z; K[17] = q6.w;
        const float2* mm = (const float2*)(means + (size_t)n * 6);
        float2 ma = mm[0], mb2 = mm[1], mc = mm[2];
        x[0] = ma.x; x[1] = ma.y; x[2] = mb2.x; x[3] = mb2.y; x[4] = mc.x; x[5] = mc.y;
    }

#pragma unroll
    for (int j = 0; j < GROUP_M; ++j) {
        int m = mg * GROUP_M + j;
        if (m >= M) break;  // uniform across block
        bool mk = mask_true(mask32, mask8, m);
        __syncthreads();  // spts reuse guard
        if (nloc < count) {
            float pt[6];
            if (mk) {
                float z0 = meas[m * 3 + 0];
                float z1 = meas[m * 3 + 1];
                float z2v = meas[m * 3 + 2];
                float i0 = hx0 - z0, i1 = hx1 - z1, i2 = hx2 - z2v;
#pragma unroll
                for (int d = 0; d < 6; ++d)
                    pt[d] = x[d] - (K[d * 3 + 0] * i0 + K[d * 3 + 1] * i1 + K[d * 3 + 2] * i2);
                float px = pt[0], py = pt[1], pz = pt[2];
                float r2 = px * px + py * py + pz * pz;
                float rho = sqrtf(r2);
                float d0 = z0 - rho;
                float d1 = z1 - atan2f(py, px);
                float d2 = z2v - asinf(pz / rho);
                float y0 = d0 / L00;
                float y1 = (d1 - L10 * y0) / L11;
                float y2 = (d2 - L20 * y0 - L21 * y1) / L22;
                float quad = y0 * y0 + y1 * y1 + y2 * y2;
                __builtin_nontemporal_store(-0.5f * quad - logdet - 2.7568156f,
                                            &logw[(size_t)m * N + n]);  // 1.5*log(2pi)
            } else {
#pragma unroll
                for (int d = 0; d < 6; ++d) pt[d] = 0.f;
                __builtin_nontemporal_store(-INFINITY, &logw[(size_t)m * N + n]);
            }
#pragma unroll
            for (int d = 0; d < 6; ++d) spts[nloc * 6 + d] = pt[d];
        }
        __syncthreads();
        int nf = count * 6;
        float* dst = pts + ((size_t)m * N + n0) * 6;
        const f32x4* s4 = (const f32x4*)spts;
        f32x4* d4 = (f32x4*)dst;
        int n4 = nf >> 2;
        for (int i = (int)threadIdx.x; i < n4; i += 256)
            __builtin_nontemporal_store(s4[i], d4 + i);
        for (int i = (n4 << 2) + (int)threadIdx.x; i < nf; i += 256)
            dst[i] = spts[i];
    }
}

// Fallback replicate (stage aliases covs slice 0): read-before-write per thread.
__global__ __launch_bounds__(256) void replicate_loop_kernel(const float* __restrict__ stage,
                                                             float* __restrict__ covs,
                                                             const int* __restrict__ mask32,
                                                             const unsigned char* __restrict__ mask8,
                                                             int N, int M) {
    int idx = blockIdx.x * blockDim.x + threadIdx.x;
    int total4 = N * 9;
    if (idx >= total4) return;
    const f32x4* s4 = (const f32x4*)stage;
    f32x4* base = (f32x4*)covs;
    f32x4 v = s4[idx];
    f32x4 z = {0.f, 0.f, 0.f, 0.f};
    for (int m = 0; m < M; ++m) {
        bool mk = mask_true(mask32, mask8, m);
        __builtin_nontemporal_store(mk ? v : z, base + (size_t)m * total4 + idx);
    }
}

extern "C" void kernel_launch(void* const* d_in, const int* in_sizes, int n_in,
                              void* d_out, int out_size, void* d_ws, size_t ws_size,
                              hipStream_t stream) {
    const float* means = (const float*)d_in[0];
    const float* meas = (const float*)d_in[3];
    const int* mask32 = (const int*)d_in[4];
    const unsigned char* mask8 = (const unsigned char*)d_in[4];
    const float* Rin = (const float*)d_in[5];

    int N = in_sizes[0] / NDIM;
    int M = in_sizes[3] / MDIM;

    float* out = (float*)d_out;
    float* pts = out;                               // [M,N,6]
    float* logw = out + (size_t)M * N * 6;          // [M,N]
    float* covs = out + (size_t)M * N * 7;          // [M,N,6,6]

    double* ws = (double*)d_ws;
    double* partials = ws;                               // 27*NB_STATS f64
    float* pack = (float*)(ws + 27 * NB_STATS);          // N*28 f32 (16B aligned)
    float* stage = pack + (size_t)N * 28;                // N*36 f32
    size_t need_pack = 27 * NB_STATS * sizeof(double) + (size_t)N * 28 * sizeof(float);
    size_t need_full = need_pack + (size_t)N * 36 * sizeof(float);

    stats_partial_kernel<<<NB_STATS, 256, 0, stream>>>(means, N, partials);

    int blocksPerM = (N + 255) / 256;
    int MG = (M + GROUP_M - 1) / GROUP_M;

    if (ws_size >= need_full) {
        particle_kernel<<<blocksPerM, 256, 0, stream>>>(means, Rin, partials, stage, pack, N);
        int RB = (N * 9 + 1023) / 1024;
        int totalBlocks = RB + blocksPerM * MG;
        fused_out_kernel<<<totalBlocks, 256, 0, stream>>>(means, meas, mask32, mask8, pack,
                                                          stage, pts, logw, covs,
                                                          N, M, RB, blocksPerM, 1);
    } else {
        // Fallback: stage in covs slice 0; update-only fused + loop replicate.
        particle_kernel<<<blocksPerM, 256, 0, stream>>>(means, Rin, partials, covs, pack, N);
        int totalBlocks = blocksPerM * MG;
        fused_out_kernel<<<totalBlocks, 256, 0, stream>>>(means, meas, mask32, mask8, pack,
                                                          covs, pts, logw, covs,
                                                          N, M, 0, blocksPerM, 0);
        replicate_loop_kernel<<<(N * 9 + 255) / 256, 256, 0, stream>>>(covs, covs, mask32,
                                                                       mask8, N, M);
    }
}